// Round 15
// baseline (122.383 us; speedup 1.0000x reference)
//
#include <hip/hip_runtime.h>
#include <stdint.h>

typedef __bf16 bf16;
typedef __attribute__((ext_vector_type(4))) __bf16 bf16x4;
typedef __attribute__((ext_vector_type(8))) __bf16 bf16x8;
typedef __attribute__((ext_vector_type(4))) float f32x4;
typedef __attribute__((ext_vector_type(4))) unsigned int u32x4;

#define W_ 160
#define H_ 96
#define C_ 128
#define B_ 16
#define HW_ (H_ * W_)            // 15360
#define NXT 10                   // 160/16
#define NYB4 24                  // 96/4: 4-row y-bands
#define NBLK (B_ * NYB4 * NXT)   // 3840 = 8*480
#define SLICEB 10240             // in2t bytes per (y,ck) slice: 160x * 4 granules * 16B
#define YB 40960                 // per (b,y): 4 slices
#define ROWSB 1536               // LDS bytes per staged row: 24 xl * 4 granules * 16B
#define CHB (12 * ROWSB)         // 18432 B per chunk (12 halo rows)
#define LDSB (2 * CHB + 512)     // 37376 B: dbuf + t=1 overread pad
#define WSSTR 464                // floats per wave epilogue region (27 rho * 17)

__device__ __forceinline__ void g2l16(const void* g, void* l) {
    __builtin_amdgcn_global_load_lds(
        (const __attribute__((address_space(1))) void*)g,
        (__attribute__((address_space(3))) void*)l, 16, 0, 0);
}

// ===== pass 1 (r11-verified): in2 [B][C][H][W] f32 -> in2t granules [b][y][ck][x*4+(g^((x>>1)&3))]
__global__ __launch_bounds__(256) void t2_kernel(const float* __restrict__ in2,
                                                 char* __restrict__ o) {
    __shared__ __align__(16) char T[40960];
    const int L   = blockIdx.x;                     // b*H_ + y
    const int tid = threadIdx.x;
    const float* src = in2 + (size_t)(L / H_) * C_ * HW_ + (size_t)(L % H_) * W_;
    char* dst = o + (size_t)L * YB;
    const float SC = 1.0f / 128.0f;                 // exact fold of 1/(K*K*C)
#pragma unroll
    for (int rd = 0; rd < 5; ++rd) {
        const int s  = rd * 256 + tid;              // 0..1279 = 32 cq x 40 x4
        const int cq = s / 40;
        const int x4 = s - cq * 40;
        const float* p = src + (size_t)(4 * cq) * HW_ + 4 * x4;
        const float4 v0 = *(const float4*)(p);
        const float4 v1 = *(const float4*)(p + HW_);
        const float4 v2 = *(const float4*)(p + 2 * HW_);
        const float4 v3 = *(const float4*)(p + 3 * HW_);
        const int oq = cq >> 1, half = cq & 1;
#pragma unroll
        for (int xj = 0; xj < 4; ++xj) {
            const int x   = 4 * x4 + xj;
            const int pos = oq ^ ((x >> 2) & 15);
            bf16x4 pk;
            pk[0] = (bf16)(((const float*)&v0)[xj] * SC);
            pk[1] = (bf16)(((const float*)&v1)[xj] * SC);
            pk[2] = (bf16)(((const float*)&v2)[xj] * SC);
            pk[3] = (bf16)(((const float*)&v3)[xj] * SC);
            *(bf16x4*)(T + x * 256 + pos * 16 + half * 8) = pk;
        }
    }
    __syncthreads();
#pragma unroll
    for (int wr = 0; wr < 10; ++wr) {
        const int s2  = wr * 256 + tid;
        const int ck  = s2 / 640;
        const int r   = s2 - ck * 640;
        const int x   = r >> 2;
        const int gsw = r & 3;
        const int gg  = gsw ^ ((x >> 1) & 3);
        const int oo  = ck * 4 + gg;
        const int pos = oo ^ ((x >> 2) & 15);
        const u32x4 v = *(const u32x4*)(T + x * 256 + pos * 16);
        *(u32x4*)(dst + (size_t)s2 * 16) = v;
    }
}

// ===== pass 2: 12-wave blocks = 4 y-rows x 3 dy-triplets; acc=24; counted dbuf pipeline
__global__ __launch_bounds__(768, 2) void corr_mfma8(const float* __restrict__ in1,
                                                     const char* __restrict__ in2t,
                                                     float* __restrict__ out) {
    __shared__ __align__(16) char Bsm[LDSB];        // 37376 B; epilogue reuses

    const int L   = ((int)blockIdx.x & 7) * (NBLK / 8) + ((int)blockIdx.x >> 3);
    const int b   = L / (NYB4 * NXT);
    const int rem = L % (NYB4 * NXT);
    const int yb  = rem / NXT;
    const int xt  = rem % NXT;
    const int x0  = xt * 16, y0 = yb * 4;

    const int tid  = threadIdx.x;
    const int wv   = __builtin_amdgcn_readfirstlane(tid >> 6);  // 0..11
    const int r    = wv & 3;             // y-row
    const int G    = wv >> 2;            // dy-triplet: dyi = 3G..3G+2
    const int lane = tid & 63;
    const int n    = lane & 15;          // frag col (A row m / B col)
    const int g    = lane >> 4;          // k-octet
    const int y    = y0 + r;

    const char* i2tb = in2t + (size_t)b * (H_ * YB);

    // ---- A fragments (per-ck batches of 8), retired before staging ----
    const float* abase = in1 + (size_t)b * C_ * HW_ + (size_t)y * W_ + (x0 + n);
    bf16x8 afrag[4];
#pragma unroll
    for (int ck = 0; ck < 4; ++ck) {
        float ar[8];
#pragma unroll
        for (int j = 0; j < 8; ++j)
            ar[j] = abase[(size_t)(ck * 32 + g * 8 + j) * HW_];
#pragma unroll
        for (int j = 0; j < 8; ++j)
            afrag[ck][j] = (bf16)ar[j];
    }
    asm volatile("s_waitcnt vmcnt(0)" ::: "memory");   // vmcnt now tracks staging only
    __builtin_amdgcn_sched_barrier(0);

    // ---- staging decode: 12 rows x 96 granules = 1152 slots; rd0 all, rd1 waves 0-5 ----
    unsigned soff[2];
#pragma unroll
    for (int rd = 0; rd < 2; ++rd) {
        const int slot = rd * 768 + tid;
        const int row  = slot / 96;                 // rd1 rows >11 never issued (wv>=6)
        const int sl   = slot - row * 96;
        const int gy   = y0 - 4 + row;
        const int gy_c = min(max(gy, 0), H_ - 1);
        const int ofs  = max((x0 - 4) * 64 + sl * 16, 0);
        soff[rd] = (unsigned)(gy_c * YB + ofs);
    }

    // ---- B-frag read offsets: granule (xl*4 + (g ^ (((x0-4+xl)>>1)&3))) * 16 ----
    int rboff[2];
#pragma unroll
    for (int t = 0; t < 2; ++t) {
        const int xl = n + 16 * t;
        const int sw = g ^ (((xl + 12) >> 1) & 3);
        rboff[t] = (xl * 4 + sw) * 16;
    }

    f32x4 acc[3][2];
#pragma unroll
    for (int j = 0; j < 3; ++j)
#pragma unroll
        for (int t = 0; t < 2; ++t)
            acc[j][t] = (f32x4){0.f, 0.f, 0.f, 0.f};

#define STAGE(CK, DST)                                                        \
    {                                                                         \
        const char* bck = i2tb + (CK) * SLICEB;                               \
        g2l16((const void*)(bck + soff[0]), (void*)((DST) + tid * 16));       \
        if (wv < 6)                                                           \
            g2l16((const void*)(bck + soff[1]),                               \
                  (void*)((DST) + (768 + tid) * 16));                         \
    }
#define WAITC1                                                                \
    {                                                                         \
        if (wv < 6) { asm volatile("s_waitcnt vmcnt(2)" ::: "memory"); }      \
        else        { asm volatile("s_waitcnt vmcnt(1)" ::: "memory"); }      \
        __builtin_amdgcn_s_barrier();                                         \
        __builtin_amdgcn_sched_barrier(0);                                    \
    }
#define WAITC0                                                                \
    {                                                                         \
        asm volatile("s_waitcnt vmcnt(0)" ::: "memory");                      \
        __builtin_amdgcn_s_barrier();                                         \
        __builtin_amdgcn_sched_barrier(0);                                    \
    }
#define RBAR                                                                  \
    {                                                                         \
        asm volatile("s_waitcnt lgkmcnt(0)" ::: "memory");                    \
        __builtin_amdgcn_s_barrier();                                         \
        __builtin_amdgcn_sched_barrier(0);                                    \
    }
#define COMPUTE(CK, BUF)                                                      \
    {                                                                         \
        _Pragma("unroll")                                                     \
        for (int j = 0; j < 3; ++j) {                                         \
            const int rowoff = (r + 3 * G + j) * ROWSB;                       \
            _Pragma("unroll")                                                 \
            for (int t = 0; t < 2; ++t) {                                     \
                const bf16x8 bfrag =                                          \
                    *(const bf16x8*)((BUF) + rowoff + rboff[t]);              \
                acc[j][t] = __builtin_amdgcn_mfma_f32_16x16x32_bf16(          \
                    afrag[CK], bfrag, acc[j][t], 0, 0, 0);                    \
            }                                                                 \
        }                                                                     \
    }

    STAGE(0, Bsm);                 // w0-5: 2 | w6-11: 1 in flight
    STAGE(1, Bsm + CHB);           // 4 | 2
    WAITC1;                        // chunk0 landed (c1 flying)
    COMPUTE(0, Bsm);
    RBAR;                          // all waves done reading B0
    STAGE(2, Bsm);                 // c1+c2 in flight
    WAITC1;                        // chunk1 landed
    COMPUTE(1, Bsm + CHB);
    RBAR;                          // all waves done reading B1
    STAGE(3, Bsm + CHB);           // c2+c3 in flight
    WAITC1;                        // chunk2 landed
    COMPUTE(2, Bsm);
    WAITC0;                        // chunk3 landed
    COMPUTE(3, Bsm + CHB);
#undef STAGE
#undef WAITC1
#undef WAITC0
#undef RBAR
#undef COMPUTE

    __syncthreads();               // all LDS reads done before ws reuse

    // ---- epilogue masks: exact-0 for OOB (x', y') ----
    float xv[2];
#pragma unroll
    for (int t = 0; t < 2; ++t)
        xv[t] = ((unsigned)(x0 - 4 + n + 16 * t) < (unsigned)W_) ? 1.f : 0.f;
    float yv[3];
#pragma unroll
    for (int j = 0; j < 3; ++j)
        yv[j] = ((unsigned)(y - 4 + 3 * G + j) < (unsigned)H_) ? 1.f : 0.f;

    // ---- epilogue (r7-verified mapping): 27 rho-planes per wave, private region ----
    float* wsw = (float*)Bsm + wv * WSSTR;          // 12*1856 B = 22272 <= 37376
#pragma unroll
    for (int j = 0; j < 3; ++j)
#pragma unroll
        for (int t = 0; t < 2; ++t)
#pragma unroll
            for (int rr = 0; rr < 4; ++rr) {
                const int m = 4 * g + rr;
                const int d = n + 16 * t - m;
                if ((unsigned)d <= 8u)
                    wsw[(j * 9 + d) * 17 + m] = acc[j][t][rr] * xv[t] * yv[j];
            }

    const int mm = lane & 15, rg = lane >> 4;
    const size_t ob = (size_t)(b * 81 + 27 * G) * HW_ + (size_t)y * W_ + (x0 + mm);
#pragma unroll
    for (int q4 = 0; q4 < 6; ++q4) {
        const int l = q4 * 4 + rg;                  // 0..23
        out[ob + (size_t)l * HW_] = wsw[l * 17 + mm];
    }
    if (rg < 3) {
        const int l = 24 + rg;                      // 24..26
        out[ob + (size_t)l * HW_] = wsw[l * 17 + mm];
    }
}

extern "C" void kernel_launch(void* const* d_in, const int* in_sizes, int n_in,
                              void* d_out, int out_size, void* d_ws, size_t ws_size,
                              hipStream_t stream) {
    const float* in1 = (const float*)d_in[0];
    const float* in2 = (const float*)d_in[1];
    float* out = (float*)d_out;
    (void)in_sizes; (void)n_in; (void)out_size; (void)ws_size;
    char* in2t = (char*)d_ws;            // 62.9 MB, fits (r8/r11-r14 verified)
    hipLaunchKernelGGL(t2_kernel, dim3(B_ * H_), dim3(256), 0, stream, in2, in2t);
    hipLaunchKernelGGL(corr_mfma8, dim3(NBLK), dim3(768), 0, stream, in1, in2t, out);
}

// Round 16
// 103.757 us; speedup vs baseline: 1.1795x; 1.1795x over previous
//
#include <hip/hip_runtime.h>
#include <stdint.h>

typedef __bf16 bf16;
typedef __attribute__((ext_vector_type(4))) __bf16 bf16x4;
typedef __attribute__((ext_vector_type(8))) __bf16 bf16x8;
typedef __attribute__((ext_vector_type(4))) float f32x4;
typedef __attribute__((ext_vector_type(4))) unsigned int u32x4;

#define W_ 160
#define H_ 96
#define C_ 128
#define B_ 16
#define HW_ (H_ * W_)            // 15360
#define NXT 10                   // 160/16
#define NYB4 24                  // 96/4: 4-row y-bands
#define NBLK (B_ * NYB4 * NXT)   // 3840 = 8*480
#define SLICEB 10240             // in2t bytes per (y,ck) slice: 160x * 4 granules * 16B
#define YB 40960                 // per (b,y): 4 slices
#define ROWSB 1536               // LDS bytes per staged row: 24 xl * 4 granules * 16B
#define CHB (12 * ROWSB)         // 18432 B per chunk (12 halo rows)
#define LDSB (2 * CHB + 512)     // 37376 B: dbuf + t=1 overread pad -> 4 blocks/CU
#define WSSTR 1408               // floats per wave epilogue region (81 rho * 17 + pad)

__device__ __forceinline__ void g2l16(const void* g, void* l) {
    __builtin_amdgcn_global_load_lds(
        (const __attribute__((address_space(1))) void*)g,
        (__attribute__((address_space(3))) void*)l, 16, 0, 0);
}

// ===== pass 1 (r11-verified, HBM-floor): in2 [B][C][H][W] f32 -> in2t granules =====
__global__ __launch_bounds__(256) void t2_kernel(const float* __restrict__ in2,
                                                 char* __restrict__ o) {
    __shared__ __align__(16) char T[40960];
    const int L   = blockIdx.x;                     // b*H_ + y
    const int tid = threadIdx.x;
    const float* src = in2 + (size_t)(L / H_) * C_ * HW_ + (size_t)(L % H_) * W_;
    char* dst = o + (size_t)L * YB;
    const float SC = 1.0f / 128.0f;                 // exact fold of 1/(K*K*C)
#pragma unroll
    for (int rd = 0; rd < 5; ++rd) {
        const int s  = rd * 256 + tid;              // 0..1279 = 32 cq x 40 x4
        const int cq = s / 40;
        const int x4 = s - cq * 40;
        const float* p = src + (size_t)(4 * cq) * HW_ + 4 * x4;
        const float4 v0 = *(const float4*)(p);
        const float4 v1 = *(const float4*)(p + HW_);
        const float4 v2 = *(const float4*)(p + 2 * HW_);
        const float4 v3 = *(const float4*)(p + 3 * HW_);
        const int oq = cq >> 1, half = cq & 1;
#pragma unroll
        for (int xj = 0; xj < 4; ++xj) {
            const int x   = 4 * x4 + xj;
            const int pos = oq ^ ((x >> 2) & 15);
            bf16x4 pk;
            pk[0] = (bf16)(((const float*)&v0)[xj] * SC);
            pk[1] = (bf16)(((const float*)&v1)[xj] * SC);
            pk[2] = (bf16)(((const float*)&v2)[xj] * SC);
            pk[3] = (bf16)(((const float*)&v3)[xj] * SC);
            *(bf16x4*)(T + x * 256 + pos * 16 + half * 8) = pk;
        }
    }
    __syncthreads();
#pragma unroll
    for (int wr = 0; wr < 10; ++wr) {
        const int s2  = wr * 256 + tid;
        const int ck  = s2 / 640;
        const int r   = s2 - ck * 640;
        const int x   = r >> 2;
        const int gsw = r & 3;
        const int gg  = gsw ^ ((x >> 1) & 3);
        const int oo  = ck * 4 + gg;
        const int pos = oo ^ ((x >> 2) & 15);
        const u32x4 v = *(const u32x4*)(T + x * 256 + pos * 16);
        *(u32x4*)(dst + (size_t)s2 * 16) = v;
    }
}

// ===== pass 2: 4-wave blocks (1 wave/SIMD), small dbuf -> 4 independent blocks/CU
__global__ __launch_bounds__(256, 4) void corr_mfma9(const float* __restrict__ in1,
                                                     const char* __restrict__ in2t,
                                                     float* __restrict__ out) {
    __shared__ __align__(16) char Bsm[LDSB];        // 37376 B; epilogue reuses

    const int L   = ((int)blockIdx.x & 7) * (NBLK / 8) + ((int)blockIdx.x >> 3);
    const int b   = L / (NYB4 * NXT);
    const int rem = L % (NYB4 * NXT);
    const int yb  = rem / NXT;
    const int xt  = rem % NXT;
    const int x0  = xt * 16, y0 = yb * 4;

    const int tid  = threadIdx.x;
    const int wv   = __builtin_amdgcn_readfirstlane(tid >> 6);  // wave 0..3 -> y row
    const int lane = tid & 63;
    const int n    = lane & 15;          // frag col (A row m / B col)
    const int g    = lane >> 4;          // k-octet
    const int y    = y0 + wv;

    const char* i2tb = in2t + (size_t)b * (H_ * YB);

    // ---- A fragments (per-ck batches of 8), retired before staging ----
    const float* abase = in1 + (size_t)b * C_ * HW_ + (size_t)y * W_ + (x0 + n);
    bf16x8 afrag[4];
#pragma unroll
    for (int ck = 0; ck < 4; ++ck) {
        float ar[8];
#pragma unroll
        for (int j = 0; j < 8; ++j)
            ar[j] = abase[(size_t)(ck * 32 + g * 8 + j) * HW_];
#pragma unroll
        for (int j = 0; j < 8; ++j)
            afrag[ck][j] = (bf16)ar[j];
    }
    asm volatile("s_waitcnt vmcnt(0)" ::: "memory");   // vmcnt now tracks staging only
    __builtin_amdgcn_sched_barrier(0);

    // ---- staging decode: 12 rows x 96 granules = 1152 slots; rounds 0-3 all,
    //      round 4 waves 0-1 (tid<128). Clamped unconditional loads (r14-proven);
    //      boundary exactness restored by epilogue masks.
    unsigned soff[5];
#pragma unroll
    for (int rd = 0; rd < 5; ++rd) {
        const int slot = rd * 256 + tid;            // rd4 used only when tid<128
        const int row  = slot / 96;
        const int sl   = slot - row * 96;
        const int gy   = y0 - 4 + row;
        const int gy_c = min(max(gy, 0), H_ - 1);
        const int ofs  = max((x0 - 4) * 64 + sl * 16, 0);
        soff[rd] = (unsigned)(gy_c * YB + ofs);
    }

    // ---- B-frag read offsets: granule (xl*4 + (g ^ (((x0-4+xl)>>1)&3))) * 16 ----
    int rboff[2];
#pragma unroll
    for (int t = 0; t < 2; ++t) {
        const int xl = n + 16 * t;
        const int sw = g ^ (((xl + 12) >> 1) & 3);
        rboff[t] = (xl * 4 + sw) * 16;
    }

    f32x4 acc[9][2];
#pragma unroll
    for (int dyi = 0; dyi < 9; ++dyi)
#pragma unroll
        for (int t = 0; t < 2; ++t)
            acc[dyi][t] = (f32x4){0.f, 0.f, 0.f, 0.f};

    // waves 0-1 issue 5 loads/STAGE, waves 2-3 issue 4 (wave-uniform branch)
#define STAGE(CK, DST)                                                        \
    {                                                                         \
        const char* bck = i2tb + (CK) * SLICEB;                               \
        g2l16((const void*)(bck + soff[0]), (void*)((DST) + tid * 16));       \
        g2l16((const void*)(bck + soff[1]), (void*)((DST) + (256 + tid) * 16)); \
        g2l16((const void*)(bck + soff[2]), (void*)((DST) + (512 + tid) * 16)); \
        g2l16((const void*)(bck + soff[3]), (void*)((DST) + (768 + tid) * 16)); \
        if (wv < 2)                                                           \
            g2l16((const void*)(bck + soff[4]),                               \
                  (void*)((DST) + (1024 + tid) * 16));                        \
    }
    // counted wait: one chunk still in flight (5 or 4 loads per wave-group)
#define WAITC                                                                 \
    {                                                                         \
        if (wv < 2) { asm volatile("s_waitcnt vmcnt(5)" ::: "memory"); }      \
        else        { asm volatile("s_waitcnt vmcnt(4)" ::: "memory"); }      \
        __builtin_amdgcn_s_barrier();                                         \
        __builtin_amdgcn_sched_barrier(0);                                    \
    }
#define WAIT0                                                                 \
    {                                                                         \
        asm volatile("s_waitcnt vmcnt(0)" ::: "memory");                      \
        __builtin_amdgcn_s_barrier();                                         \
        __builtin_amdgcn_sched_barrier(0);                                    \
    }
#define RBAR                                                                  \
    {                                                                         \
        asm volatile("s_waitcnt lgkmcnt(0)" ::: "memory");                    \
        __builtin_amdgcn_s_barrier();                                         \
        __builtin_amdgcn_sched_barrier(0);                                    \
    }
#define COMPUTE(CK, BUF)                                                      \
    {                                                                         \
        _Pragma("unroll")                                                     \
        for (int dyi = 0; dyi < 9; ++dyi) {                                   \
            const int rowoff = (wv + dyi) * ROWSB;                            \
            _Pragma("unroll")                                                 \
            for (int t = 0; t < 2; ++t) {                                     \
                const bf16x8 bfrag =                                          \
                    *(const bf16x8*)((BUF) + rowoff + rboff[t]);              \
                acc[dyi][t] = __builtin_amdgcn_mfma_f32_16x16x32_bf16(        \
                    afrag[CK], bfrag, acc[dyi][t], 0, 0, 0);                  \
            }                                                                 \
        }                                                                     \
    }

    STAGE(0, Bsm);                 // w01: 5 | w23: 4 in flight
    STAGE(1, Bsm + CHB);           // 10 | 8
    WAITC;                         // chunk0 landed (c1 flying)
    COMPUTE(0, Bsm);
    RBAR;                          // all waves done reading B0
    STAGE(2, Bsm);                 // c1+c2 in flight
    WAITC;                         // chunk1 landed
    COMPUTE(1, Bsm + CHB);
    RBAR;                          // all waves done reading B1
    STAGE(3, Bsm + CHB);           // c2+c3 in flight
    WAITC;                         // chunk2 landed
    COMPUTE(2, Bsm);
    WAIT0;                         // chunk3 landed
    COMPUTE(3, Bsm + CHB);
#undef STAGE
#undef WAITC
#undef WAIT0
#undef RBAR
#undef COMPUTE

    __syncthreads();               // all LDS reads done before ws reuse

    // ---- epilogue masks: exact-0 for OOB (x', y') — r8/r10/r14-verified ----
    float xv[2];
#pragma unroll
    for (int t = 0; t < 2; ++t)
        xv[t] = ((unsigned)(x0 - 4 + n + 16 * t) < (unsigned)W_) ? 1.f : 0.f;
    float yv[9];
#pragma unroll
    for (int dyi = 0; dyi < 9; ++dyi)
        yv[dyi] = ((unsigned)(y - 4 + dyi) < (unsigned)H_) ? 1.f : 0.f;

    // ---- epilogue (r7-verified mapping, stride 17, per-wave private region) ----
    float* wsw = (float*)Bsm + wv * WSSTR;          // 4*5632 B = 22528 <= 37376
#pragma unroll
    for (int dyi = 0; dyi < 9; ++dyi)
#pragma unroll
        for (int t = 0; t < 2; ++t)
#pragma unroll
            for (int rr = 0; rr < 4; ++rr) {
                const int m = 4 * g + rr;
                const int d = n + 16 * t - m;
                if ((unsigned)d <= 8u)
                    wsw[(dyi * 9 + d) * 17 + m] = acc[dyi][t][rr] * xv[t] * yv[dyi];
            }

    const int mm = lane & 15, rg = lane >> 4;
    const size_t ob = (size_t)(b * 81) * HW_ + (size_t)y * W_ + (x0 + mm);
#pragma unroll
    for (int q4 = 0; q4 < 20; ++q4) {
        const int rho = q4 * 4 + rg;
        out[ob + (size_t)rho * HW_] = wsw[rho * 17 + mm];
    }
    if (rg == 0)
        out[ob + (size_t)80 * HW_] = wsw[80 * 17 + mm];
}

extern "C" void kernel_launch(void* const* d_in, const int* in_sizes, int n_in,
                              void* d_out, int out_size, void* d_ws, size_t ws_size,
                              hipStream_t stream) {
    const float* in1 = (const float*)d_in[0];
    const float* in2 = (const float*)d_in[1];
    float* out = (float*)d_out;
    (void)in_sizes; (void)n_in; (void)out_size; (void)ws_size;
    char* in2t = (char*)d_ws;            // 62.9 MB, fits (r8/r11-r15 verified)
    hipLaunchKernelGGL(t2_kernel, dim3(B_ * H_), dim3(256), 0, stream, in2, in2t);
    hipLaunchKernelGGL(corr_mfma9, dim3(NBLK), dim3(256), 0, stream, in1, in2t, out);
}